// Round 1
// baseline (5979.999 us; speedup 1.0000x reference)
//
#include <hip/hip_runtime.h>
#include <math.h>

#define SD 2048
#define BD 4096

// ---------------- tiled fp32 GEMM ----------------
// MODE 0: C = A*B
// MODE 1: C = alpha*(A*B) + I            (Horner step for Taylor expm)
// MODE 2: out = (acc*rnorm[i] + bias[j])^2 * gate[j]   (final epilogue)
#define BM 128
#define BN 128
#define BK 16

template<int MODE>
__global__ __launch_bounds__(256)
void gemm_k(const float* __restrict__ A, const float* __restrict__ B,
            float* __restrict__ C, int M, int N, int K, float alpha,
            const float* __restrict__ rnorm, const float* __restrict__ bias,
            const float* __restrict__ gate)
{
    __shared__ float As[BK][BM];
    __shared__ float Bs[BK][BN];
    const int tid  = threadIdx.x;
    const int row0 = blockIdx.y * BM;
    const int col0 = blockIdx.x * BN;
    const int tx = tid & 15, ty = tid >> 4;

    float c[8][8];
#pragma unroll
    for (int i = 0; i < 8; ++i)
#pragma unroll
        for (int j = 0; j < 8; ++j) c[i][j] = 0.f;

    const float* Ap = A + (size_t)row0 * K;
    const float* Bp = B + col0;

    // staging index map (256 threads)
    const int ar = tid >> 2;          // 0..63  (A rows, +64 for second half)
    const int ak = (tid & 3) << 2;    // 0,4,8,12 (k within slab, float4)
    const int bk = tid >> 5;          // 0..7   (B rows, +8 for second half)
    const int bc = (tid & 31) << 2;   // 0..124 (B cols, float4)

    float4 av0, av1, bv0, bv1;
    av0 = *(const float4*)(Ap + (size_t)ar        * K + ak);
    av1 = *(const float4*)(Ap + (size_t)(ar + 64) * K + ak);
    bv0 = *(const float4*)(Bp + (size_t)bk        * N + bc);
    bv1 = *(const float4*)(Bp + (size_t)(bk + 8)  * N + bc);

    for (int k0 = 0; k0 < K; k0 += BK) {
        __syncthreads();
        As[ak + 0][ar]      = av0.x; As[ak + 1][ar]      = av0.y;
        As[ak + 2][ar]      = av0.z; As[ak + 3][ar]      = av0.w;
        As[ak + 0][ar + 64] = av1.x; As[ak + 1][ar + 64] = av1.y;
        As[ak + 2][ar + 64] = av1.z; As[ak + 3][ar + 64] = av1.w;
        *(float4*)&Bs[bk][bc]     = bv0;
        *(float4*)&Bs[bk + 8][bc] = bv1;
        __syncthreads();
        const int kn = k0 + BK;
        if (kn < K) {   // prefetch next slab (overlaps with compute below)
            av0 = *(const float4*)(Ap + (size_t)ar        * K + kn + ak);
            av1 = *(const float4*)(Ap + (size_t)(ar + 64) * K + kn + ak);
            bv0 = *(const float4*)(Bp + (size_t)(kn + bk)     * N + bc);
            bv1 = *(const float4*)(Bp + (size_t)(kn + bk + 8) * N + bc);
        }
#pragma unroll
        for (int kk = 0; kk < BK; ++kk) {
            float a[8], b[8];
            *(float4*)&a[0] = *(const float4*)&As[kk][(ty << 2)];
            *(float4*)&a[4] = *(const float4*)&As[kk][64 + (ty << 2)];
            *(float4*)&b[0] = *(const float4*)&Bs[kk][(tx << 2)];
            *(float4*)&b[4] = *(const float4*)&Bs[kk][64 + (tx << 2)];
#pragma unroll
            for (int i = 0; i < 8; ++i)
#pragma unroll
                for (int j = 0; j < 8; ++j)
                    c[i][j] = fmaf(a[i], b[j], c[i][j]);
        }
    }

#pragma unroll
    for (int i = 0; i < 8; ++i) {
        const int mr = (i < 4) ? ((ty << 2) + i) : (64 + (ty << 2) + (i - 4));
        const int gr = row0 + mr;
        float rn = 0.f;
        if (MODE == 2) rn = rnorm[gr];
#pragma unroll
        for (int jg = 0; jg < 2; ++jg) {
            const int gc = col0 + (jg ? 64 : 0) + (tx << 2);
            float vv[4];
#pragma unroll
            for (int f = 0; f < 4; ++f) {
                const float acc = c[i][(jg << 2) + f];
                if (MODE == 0) {
                    vv[f] = acc;
                } else if (MODE == 1) {
                    vv[f] = alpha * acc + ((gr == gc + f) ? 1.f : 0.f);
                } else {
                    const float t = fmaf(acc, rn, bias[gc + f]);
                    vv[f] = t * t * gate[gc + f];
                }
            }
            *(float4*)(C + (size_t)gr * N + gc) = *(float4*)vv;
        }
    }
}

// X = (M - M^T) * scale  (tiled transpose, both reads coalesced)
__global__ __launch_bounds__(256)
void skew_k(const float* __restrict__ M, float* __restrict__ X, float scale)
{
    __shared__ float t1[32][33];
    __shared__ float t2[32][33];
    const int bx = blockIdx.x * 32, by = blockIdx.y * 32;
    const int tx = threadIdx.x, ty = threadIdx.y;  // 32 x 8
#pragma unroll
    for (int r = 0; r < 32; r += 8) {
        t1[ty + r][tx] = M[(size_t)(by + ty + r) * SD + bx + tx];
        t2[ty + r][tx] = M[(size_t)(bx + ty + r) * SD + by + tx];
    }
    __syncthreads();
#pragma unroll
    for (int r = 0; r < 32; r += 8)
        X[(size_t)(by + ty + r) * SD + bx + tx] =
            (t1[ty + r][tx] - t2[tx][ty + r]) * scale;
}

// T = a*X + I   (innermost Horner term)
__global__ __launch_bounds__(256)
void axpyI_k(const float* __restrict__ X, float* __restrict__ T, float a)
{
    const size_t idx  = (size_t)blockIdx.x * blockDim.x + threadIdx.x;
    const size_t base = idx << 2;
    const int i = (int)(base >> 11);      // row (SD = 2048)
    const int j = (int)(base & 2047);     // col of first elem
    float4 v = *(const float4*)(X + base);
    float o[4];
    o[0] = a * v.x + ((i == j + 0) ? 1.f : 0.f);
    o[1] = a * v.y + ((i == j + 1) ? 1.f : 0.f);
    o[2] = a * v.z + ((i == j + 2) ? 1.f : 0.f);
    o[3] = a * v.w + ((i == j + 3) ? 1.f : 0.f);
    *(float4*)(T + base) = *(float4*)o;
}

// rnorm[row] = 1/sqrt(max(sum(x^2), 1e-12))
__global__ __launch_bounds__(256)
void rownorm_k(const float* __restrict__ in, float* __restrict__ rn)
{
    const int row = blockIdx.x;
    const float4* p = (const float4*)(in + (size_t)row * SD);
    float ss = 0.f;
    for (int i = threadIdx.x; i < SD / 4; i += 256) {
        float4 v = p[i];
        ss += v.x * v.x + v.y * v.y;
        ss += v.z * v.z + v.w * v.w;
    }
#pragma unroll
    for (int o = 32; o; o >>= 1) ss += __shfl_down(ss, o);
    __shared__ float part[4];
    if ((threadIdx.x & 63) == 0) part[threadIdx.x >> 6] = ss;
    __syncthreads();
    if (threadIdx.x == 0) {
        const float t = part[0] + part[1] + part[2] + part[3];
        rn[row] = 1.0f / sqrtf(fmaxf(t, 1e-12f));
    }
}

// p = softmax(q) over SD elements, single block
__global__ __launch_bounds__(256)
void softmax_k(const float* __restrict__ q, float* __restrict__ p)
{
    __shared__ float red[4];
    const int tid = threadIdx.x;
    float m = -INFINITY;
    for (int i = tid; i < SD; i += 256) m = fmaxf(m, q[i]);
#pragma unroll
    for (int o = 32; o; o >>= 1) m = fmaxf(m, __shfl_down(m, o));
    if ((tid & 63) == 0) red[tid >> 6] = m;
    __syncthreads();
    const float gm = fmaxf(fmaxf(red[0], red[1]), fmaxf(red[2], red[3]));
    float s = 0.f;
    for (int i = tid; i < SD; i += 256) {
        const float e = expf(q[i] - gm);
        p[i] = e;
        s += e;
    }
#pragma unroll
    for (int o = 32; o; o >>= 1) s += __shfl_down(s, o);
    __syncthreads();
    if ((tid & 63) == 0) red[tid >> 6] = s;
    __syncthreads();
    const float inv = 1.0f / (red[0] + red[1] + red[2] + red[3]);
    for (int i = tid; i < SD; i += 256) p[i] *= inv;
}

extern "C" void kernel_launch(void* const* d_in, const int* in_sizes, int n_in,
                              void* d_out, int out_size, void* d_ws, size_t ws_size,
                              hipStream_t stream)
{
    const float* inputs = (const float*)d_in[0];
    const float* Mr     = (const float*)d_in[1];
    const float* Mi     = (const float*)d_in[2];
    const float* bias   = (const float*)d_in[3];
    const float* qg     = (const float*)d_in[4];
    float* out = (float*)d_out;
    float* ws  = (float*)d_ws;

    const size_t SL = (size_t)SD * SD;      // 4 Mi elems = 16 MB
    float* ws0   = ws;                      // EA (then persists)
    float* ws1   = ws + SL;                 // scratch -> EB
    float* ws2   = ws + 2 * SL;             // scratch -> U
    float* rnorm = ws + 3 * SL;             // 4096 floats
    float* d0    = out;                     // d_out scratch slot 0 (first 16 MB)
    float* d1    = out + SL;                // d_out scratch slot 1 (second 16 MB)
    float* gate  = out + (size_t)BD * SD;   // gate_probs tail (written once, final)

    const dim3 tb(256);
    const dim3 gsq(SD / BN, SD / BM);       // (16,16)
    const dim3 gbt(SD / BN, BD / BM);       // (16,32)
    const dim3 gtr(SD / 32, SD / 32);       // (64,64)
    const dim3 ttr(32, 8);
    const int axblocks = (int)(SL / 4 / 256);
    const float SCALE = 1.0f / 64.0f;       // s = 6 squarings; theta ~ 12.8/64 = 0.2

    // small ops
    softmax_k<<<1, tb, 0, stream>>>(qg, gate);
    rownorm_k<<<BD, tb, 0, stream>>>(inputs, rnorm);

    // ---- EA = expm(Mr - Mr^T), degree-6 Taylor Horner + 6 squarings ----
    skew_k<<<gtr, ttr, 0, stream>>>(Mr, d0, SCALE);
    axpyI_k<<<axblocks, tb, 0, stream>>>(d0, d1, 1.0f / 6.0f);
    gemm_k<1><<<gsq, tb, 0, stream>>>(d0, d1,  ws1, SD, SD, SD, 1.0f / 5.0f, nullptr, nullptr, nullptr);
    gemm_k<1><<<gsq, tb, 0, stream>>>(d0, ws1, d1,  SD, SD, SD, 1.0f / 4.0f, nullptr, nullptr, nullptr);
    gemm_k<1><<<gsq, tb, 0, stream>>>(d0, d1,  ws1, SD, SD, SD, 1.0f / 3.0f, nullptr, nullptr, nullptr);
    gemm_k<1><<<gsq, tb, 0, stream>>>(d0, ws1, d1,  SD, SD, SD, 0.5f,        nullptr, nullptr, nullptr);
    gemm_k<1><<<gsq, tb, 0, stream>>>(d0, d1,  ws1, SD, SD, SD, 1.0f,        nullptr, nullptr, nullptr);
    // squarings: ws1 -> d1 -> d0 -> d1 -> d0 -> d1 -> ws0
    gemm_k<0><<<gsq, tb, 0, stream>>>(ws1, ws1, d1,  SD, SD, SD, 0.f, nullptr, nullptr, nullptr);
    gemm_k<0><<<gsq, tb, 0, stream>>>(d1,  d1,  d0,  SD, SD, SD, 0.f, nullptr, nullptr, nullptr);
    gemm_k<0><<<gsq, tb, 0, stream>>>(d0,  d0,  d1,  SD, SD, SD, 0.f, nullptr, nullptr, nullptr);
    gemm_k<0><<<gsq, tb, 0, stream>>>(d1,  d1,  d0,  SD, SD, SD, 0.f, nullptr, nullptr, nullptr);
    gemm_k<0><<<gsq, tb, 0, stream>>>(d0,  d0,  d1,  SD, SD, SD, 0.f, nullptr, nullptr, nullptr);
    gemm_k<0><<<gsq, tb, 0, stream>>>(d1,  d1,  ws0, SD, SD, SD, 0.f, nullptr, nullptr, nullptr);

    // ---- EB = expm(Mi - Mi^T) ----
    skew_k<<<gtr, ttr, 0, stream>>>(Mi, d0, SCALE);
    axpyI_k<<<axblocks, tb, 0, stream>>>(d0, d1, 1.0f / 6.0f);
    gemm_k<1><<<gsq, tb, 0, stream>>>(d0, d1,  ws2, SD, SD, SD, 1.0f / 5.0f, nullptr, nullptr, nullptr);
    gemm_k<1><<<gsq, tb, 0, stream>>>(d0, ws2, d1,  SD, SD, SD, 1.0f / 4.0f, nullptr, nullptr, nullptr);
    gemm_k<1><<<gsq, tb, 0, stream>>>(d0, d1,  ws2, SD, SD, SD, 1.0f / 3.0f, nullptr, nullptr, nullptr);
    gemm_k<1><<<gsq, tb, 0, stream>>>(d0, ws2, d1,  SD, SD, SD, 0.5f,        nullptr, nullptr, nullptr);
    gemm_k<1><<<gsq, tb, 0, stream>>>(d0, d1,  ws2, SD, SD, SD, 1.0f,        nullptr, nullptr, nullptr);
    // squarings: ws2 -> d1 -> d0 -> d1 -> d0 -> d1 -> ws1
    gemm_k<0><<<gsq, tb, 0, stream>>>(ws2, ws2, d1,  SD, SD, SD, 0.f, nullptr, nullptr, nullptr);
    gemm_k<0><<<gsq, tb, 0, stream>>>(d1,  d1,  d0,  SD, SD, SD, 0.f, nullptr, nullptr, nullptr);
    gemm_k<0><<<gsq, tb, 0, stream>>>(d0,  d0,  d1,  SD, SD, SD, 0.f, nullptr, nullptr, nullptr);
    gemm_k<0><<<gsq, tb, 0, stream>>>(d1,  d1,  d0,  SD, SD, SD, 0.f, nullptr, nullptr, nullptr);
    gemm_k<0><<<gsq, tb, 0, stream>>>(d0,  d0,  d1,  SD, SD, SD, 0.f, nullptr, nullptr, nullptr);
    gemm_k<0><<<gsq, tb, 0, stream>>>(d1,  d1,  ws1, SD, SD, SD, 0.f, nullptr, nullptr, nullptr);

    // ---- U = EA * EB ----
    gemm_k<0><<<gsq, tb, 0, stream>>>(ws0, ws1, ws2, SD, SD, SD, 0.f, nullptr, nullptr, nullptr);

    // ---- out = ((inputs @ U) * rnorm_i + bias_j)^2 * gate_j ----
    gemm_k<2><<<gbt, tb, 0, stream>>>(inputs, ws2, out, BD, SD, SD, 0.f, rnorm, bias, gate);

    (void)in_sizes; (void)n_in; (void)out_size; (void)ws_size;
}

// Round 2
// 3288.564 us; speedup vs baseline: 1.8184x; 1.8184x over previous
//
#include <hip/hip_runtime.h>
#include <math.h>

#define SD 2048
#define BDIM 4096

typedef _Float16 f16;
using f16x8 = __attribute__((ext_vector_type(8))) f16;
using f16x4 = __attribute__((ext_vector_type(4))) f16;
using f32x4 = __attribute__((ext_vector_type(4))) float;

#define EPS_CROSS 4.8828125e-4f   // 2^-11
#define LSCALE    2048.0f         // 2^11

__device__ __forceinline__ void fsplit(float x, f16& h, f16& l) {
    h = (f16)x;
    l = (f16)((x - (float)h) * LSCALE);
}
__device__ __forceinline__ float fcomb(f16 h, f16 l) {
    return (float)h + (float)l * EPS_CROSS;
}
__device__ __forceinline__ float f4get(const float4& v, int j) {
    return j == 0 ? v.x : j == 1 ? v.y : j == 2 ? v.z : v.w;
}

template<int ASRC, int OUT>
__global__ __launch_bounds__(256, 2)
void gsplit_k(const f16* __restrict__ Ahi, const f16* __restrict__ Alo,
              const float* __restrict__ A32, const float* __restrict__ Ascale,
              const f16* __restrict__ Bhi, const f16* __restrict__ Blo,
              f16* __restrict__ CAhi, f16* __restrict__ CAlo, float sA, float dA,
              f16* __restrict__ C2hi, f16* __restrict__ C2lo, float s2, float d2,
              f16* __restrict__ CBhi, f16* __restrict__ CBlo, float sB, float dB,
              float* __restrict__ C32, const float* __restrict__ bias,
              const float* __restrict__ gate)
{
    __shared__ f16 Ah[4*128*8], Al[4*128*8], Bh[4*64*8], Bl[4*64*8];
    const int tid  = threadIdx.x;
    const int row0 = blockIdx.y * 128, col0 = blockIdx.x * 64;

    const int srow = tid >> 1;
    const int sks  = (tid & 1) << 4;
    const int kg0  = (tid & 1) * 2;
    const int bcol = tid & 63;
    const int bkg  = tid >> 6;

    float ascale = 1.f;
    if (ASRC == 1) ascale = Ascale ? Ascale[row0 + srow] : 1.f;

    const size_t abase = (size_t)(row0 + srow) * SD;
    const size_t bbase = (size_t)(col0 + bcol) * SD;

    float4 ra[4], rb0, rb1;

    auto loadT = [&](int k0) {
        if (ASRC == 0) {
            ra[0] = *(const float4*)(Ahi + abase + k0 + sks);
            ra[1] = *(const float4*)(Ahi + abase + k0 + sks + 8);
            ra[2] = *(const float4*)(Alo + abase + k0 + sks);
            ra[3] = *(const float4*)(Alo + abase + k0 + sks + 8);
        } else {
            const float* p = A32 + abase + k0 + sks;
            ra[0] = *(const float4*)(p);
            ra[1] = *(const float4*)(p + 4);
            ra[2] = *(const float4*)(p + 8);
            ra[3] = *(const float4*)(p + 12);
        }
        rb0 = *(const float4*)(Bhi + bbase + k0 + bkg*8);
        rb1 = *(const float4*)(Blo + bbase + k0 + bkg*8);
    };
    auto storeT = [&]() {
        if (ASRC == 0) {
            *(float4*)&Ah[((kg0+0)*128 + srow)*8] = ra[0];
            *(float4*)&Ah[((kg0+1)*128 + srow)*8] = ra[1];
            *(float4*)&Al[((kg0+0)*128 + srow)*8] = ra[2];
            *(float4*)&Al[((kg0+1)*128 + srow)*8] = ra[3];
        } else {
            f16x8 h0, h1, l0, l1;
            #pragma unroll
            for (int j = 0; j < 8; ++j) {
                f16 hh, ll;
                fsplit(f4get(ra[j >> 2], j & 3) * ascale, hh, ll);
                h0[j] = hh; l0[j] = ll;
                fsplit(f4get(ra[2 + (j >> 2)], j & 3) * ascale, hh, ll);
                h1[j] = hh; l1[j] = ll;
            }
            *(f16x8*)&Ah[((kg0+0)*128 + srow)*8] = h0;
            *(f16x8*)&Ah[((kg0+1)*128 + srow)*8] = h1;
            *(f16x8*)&Al[((kg0+0)*128 + srow)*8] = l0;
            *(f16x8*)&Al[((kg0+1)*128 + srow)*8] = l1;
        }
        *(float4*)&Bh[(bkg*64 + bcol)*8] = rb0;
        *(float4*)&Bl[(bkg*64 + bcol)*8] = rb1;
    };

    const int lane = tid & 63, lr = lane & 15, lg = lane >> 4;
    const int wm = (tid >> 6) & 1, wn = tid >> 7;

    f32x4 ch[4][2], cx[4][2];
    #pragma unroll
    for (int m = 0; m < 4; ++m)
    #pragma unroll
    for (int n = 0; n < 2; ++n) {
        ch[m][n] = (f32x4)0.f;
        cx[m][n] = (f32x4)0.f;
    }

    loadT(0);
    for (int k0 = 0; k0 < SD; k0 += 32) {
        __syncthreads();
        storeT();
        __syncthreads();
        if (k0 + 32 < SD) loadT(k0 + 32);

        f16x8 af[4][2], bf[2][2];
        #pragma unroll
        for (int m = 0; m < 4; ++m) {
            const int off = (lg*128 + wm*64 + m*16 + lr)*8;
            af[m][0] = *(const f16x8*)&Ah[off];
            af[m][1] = *(const f16x8*)&Al[off];
        }
        #pragma unroll
        for (int n = 0; n < 2; ++n) {
            const int off = (lg*64 + wn*32 + n*16 + lr)*8;
            bf[n][0] = *(const f16x8*)&Bh[off];
            bf[n][1] = *(const f16x8*)&Bl[off];
        }
        #pragma unroll
        for (int m = 0; m < 4; ++m)
        #pragma unroll
        for (int n = 0; n < 2; ++n) {
            ch[m][n] = __builtin_amdgcn_mfma_f32_16x16x32_f16(af[m][0], bf[n][0], ch[m][n], 0, 0, 0);
            cx[m][n] = __builtin_amdgcn_mfma_f32_16x16x32_f16(af[m][0], bf[n][1], cx[m][n], 0, 0, 0);
            cx[m][n] = __builtin_amdgcn_mfma_f32_16x16x32_f16(af[m][1], bf[n][0], cx[m][n], 0, 0, 0);
        }
    }

    const int rb = row0 + wm*64, cb = col0 + wn*32;
    #pragma unroll
    for (int m = 0; m < 4; ++m)
    #pragma unroll
    for (int n = 0; n < 2; ++n) {
        const int gr0 = rb + m*16 + lg*4;
        const int gc  = cb + n*16 + lr;
        float v[4];
        #pragma unroll
        for (int q = 0; q < 4; ++q)
            v[q] = ch[m][n][q] + EPS_CROSS * cx[m][n][q];

        if (OUT == 0) {
            if (CAhi) {
                #pragma unroll
                for (int q = 0; q < 4; ++q) {
                    float va = sA * v[q] + ((gr0 + q) == gc ? dA : 0.f);
                    f16 h, l; fsplit(va, h, l);
                    CAhi[(size_t)(gr0+q)*SD + gc] = h;
                    CAlo[(size_t)(gr0+q)*SD + gc] = l;
                }
            }
            if (C2hi) {
                #pragma unroll
                for (int q = 0; q < 4; ++q) {
                    float v2 = s2 * v[q] + ((gr0 + q) == gc ? d2 : 0.f);
                    f16 h, l; fsplit(v2, h, l);
                    C2hi[(size_t)(gr0+q)*SD + gc] = h;
                    C2lo[(size_t)(gr0+q)*SD + gc] = l;
                }
            }
            if (CBhi) {
                f16x4 hb, lb;
                #pragma unroll
                for (int q = 0; q < 4; ++q) {
                    float vb = sB * v[q] + ((gr0 + q) == gc ? dB : 0.f);
                    f16 h, l; fsplit(vb, h, l);
                    hb[q] = h; lb[q] = l;
                }
                *(f16x4*)&CBhi[(size_t)gc*SD + gr0] = hb;
                *(f16x4*)&CBlo[(size_t)gc*SD + gr0] = lb;
            }
        } else if (OUT == 1) {
            #pragma unroll
            for (int q = 0; q < 4; ++q)
                C32[(size_t)(gr0+q)*SD + gc] = v[q];
        } else {
            #pragma unroll
            for (int q = 0; q < 4; ++q) {
                float t = v[q] + bias[gc];
                C32[(size_t)(gr0+q)*SD + gc] = t * t * gate[gc];
            }
        }
    }
}

__global__ __launch_bounds__(256)
void skew_split_k(const float* __restrict__ M,
                  f16* __restrict__ XAh, f16* __restrict__ XAl,
                  f16* __restrict__ XBh, f16* __restrict__ XBl, float scale)
{
    __shared__ float t1[32][33], t2[32][33];
    const int bx = blockIdx.x*32, by = blockIdx.y*32;
    const int tx = threadIdx.x, ty = threadIdx.y;
    #pragma unroll
    for (int r = 0; r < 32; r += 8) {
        t1[ty+r][tx] = M[(size_t)(by+ty+r)*SD + bx+tx];
        t2[ty+r][tx] = M[(size_t)(bx+ty+r)*SD + by+tx];
    }
    __syncthreads();
    #pragma unroll
    for (int r = 0; r < 32; r += 8) {
        float xs = (t1[ty+r][tx] - t2[tx][ty+r]) * scale;
        size_t idx = (size_t)(by+ty+r)*SD + bx+tx;
        f16 h, l;
        fsplit(xs, h, l);  XAh[idx] = h; XAl[idx] = l;
        fsplit(-xs, h, l); XBh[idx] = h; XBl[idx] = l;
    }
}

__global__ __launch_bounds__(256)
void eadd_k(const float* __restrict__ M, float scale,
            float cA, f16* __restrict__ Ahp, f16* __restrict__ Alp,
            float cB, f16* __restrict__ Bhp, f16* __restrict__ Blp)
{
    __shared__ float t1[32][33], t2[32][33];
    const int bx = blockIdx.x*32, by = blockIdx.y*32;
    const int tx = threadIdx.x, ty = threadIdx.y;
    #pragma unroll
    for (int r = 0; r < 32; r += 8) {
        t1[ty+r][tx] = M[(size_t)(by+ty+r)*SD + bx+tx];
        t2[ty+r][tx] = M[(size_t)(bx+ty+r)*SD + by+tx];
    }
    __syncthreads();
    #pragma unroll
    for (int r = 0; r < 32; r += 8) {
        float xs = (t1[ty+r][tx] - t2[tx][ty+r]) * scale;
        size_t idx = (size_t)(by+ty+r)*SD + bx+tx;
        f16 h, l;
        float va = fcomb(Ahp[idx], Alp[idx]) + cA * xs;
        fsplit(va, h, l); Ahp[idx] = h; Alp[idx] = l;
        if (Bhp) {
            float vb = fcomb(Bhp[idx], Blp[idx]) + cB * xs;
            fsplit(vb, h, l); Bhp[idx] = h; Blp[idx] = l;
        }
    }
}

__global__ __launch_bounds__(256)
void rownorm_k(const float* __restrict__ in, float* __restrict__ rn)
{
    const int row = blockIdx.x;
    const float4* p = (const float4*)(in + (size_t)row * SD);
    float ss = 0.f;
    for (int i = threadIdx.x; i < SD / 4; i += 256) {
        float4 v = p[i];
        ss += v.x*v.x + v.y*v.y + v.z*v.z + v.w*v.w;
    }
#pragma unroll
    for (int o = 32; o; o >>= 1) ss += __shfl_down(ss, o);
    __shared__ float part[4];
    if ((threadIdx.x & 63) == 0) part[threadIdx.x >> 6] = ss;
    __syncthreads();
    if (threadIdx.x == 0) {
        const float t = part[0] + part[1] + part[2] + part[3];
        rn[row] = 1.0f / sqrtf(fmaxf(t, 1e-12f));
    }
}

__global__ __launch_bounds__(256)
void softmax_k(const float* __restrict__ q, float* __restrict__ pws,
               float* __restrict__ pout)
{
    __shared__ float red[4];
    const int tid = threadIdx.x;
    float m = -INFINITY;
    for (int i = tid; i < SD; i += 256) m = fmaxf(m, q[i]);
#pragma unroll
    for (int o = 32; o; o >>= 1) m = fmaxf(m, __shfl_down(m, o));
    if ((tid & 63) == 0) red[tid >> 6] = m;
    __syncthreads();
    const float gm = fmaxf(fmaxf(red[0], red[1]), fmaxf(red[2], red[3]));
    float s = 0.f;
    for (int i = tid; i < SD; i += 256) s += expf(q[i] - gm);
#pragma unroll
    for (int o = 32; o; o >>= 1) s += __shfl_down(s, o);
    __syncthreads();
    if ((tid & 63) == 0) red[tid >> 6] = s;
    __syncthreads();
    const float inv = 1.0f / (red[0] + red[1] + red[2] + red[3]);
    for (int i = tid; i < SD; i += 256) {
        const float val = expf(q[i] - gm) * inv;
        pws[i] = val;
        pout[i] = val;
    }
}

static void launch_g00(dim3 g, hipStream_t s,
                       f16* Ah, f16* Al, f16* Bh, f16* Bl,
                       f16* CAh, f16* CAl, float sA, float dA,
                       f16* C2h, f16* C2l, float s2, float d2,
                       f16* CBh, f16* CBl, float sB, float dB)
{
    gsplit_k<0,0><<<g, dim3(256), 0, s>>>(Ah, Al, nullptr, nullptr, Bh, Bl,
        CAh, CAl, sA, dA, C2h, C2l, s2, d2, CBh, CBl, sB, dB,
        nullptr, nullptr, nullptr);
}

extern "C" void kernel_launch(void* const* d_in, const int* in_sizes, int n_in,
                              void* d_out, int out_size, void* d_ws, size_t ws_size,
                              hipStream_t stream)
{
    const float* inputs = (const float*)d_in[0];
    const float* Mr     = (const float*)d_in[1];
    const float* Mi     = (const float*)d_in[2];
    const float* bias   = (const float*)d_in[3];
    const float* qg     = (const float*)d_in[4];
    float* out = (float*)d_out;

    const size_t PL = (size_t)8 * 1024 * 1024;
    char* wsb = (char*)d_ws;
    char* ob  = (char*)d_out;
    f16* W[6]; f16* D[4];
    for (int i = 0; i < 6; ++i) W[i] = (f16*)(wsb + (size_t)i * PL);
    for (int i = 0; i < 4; ++i) D[i] = (f16*)(ob  + (size_t)i * PL);
    float* Yws   = (float*)(wsb + 2 * PL);
    float* rnorm = (float*)(wsb + 6 * PL);
    float* gatew = rnorm + 4096;
    float* gout  = out + (size_t)BDIM * SD;

    const float c2 = 0.5f, c3 = 1.f/6.f, c4 = 1.f/24.f, c5 = 1.f/120.f, c6 = 1.f/720.f;
    const float SC = 1.0f / 32.0f;

    const dim3 tb(256);
    const dim3 gsq(SD/64, SD/128);
    const dim3 gbt(SD/64, BDIM/128);
    const dim3 gtr(SD/32, SD/32), ttr(32, 8);

    rownorm_k<<<BDIM, tb, 0, stream>>>(inputs, rnorm);
    softmax_k<<<1, tb, 0, stream>>>(qg, gatew, gout);

    // ---------------- chain A (Mr) -> EA_B @ (D0,D1) ----------------
    skew_split_k<<<gtr, ttr, 0, stream>>>(Mr, W[0], W[1], W[2], W[3], SC);
    gsplit_k<0,0><<<gsq, tb, 0, stream>>>(W[0], W[1], nullptr, nullptr, W[2], W[3],
        W[4], W[5], c6, c4, D[0], D[1], 1.f, 0.f, nullptr, nullptr, 0.f, 0.f,
        nullptr, nullptr, nullptr);                                     // M0'=c6*Y+c4I ; Y->(D0,D1)
    eadd_k<<<gtr, ttr, 0, stream>>>(Mr, SC, c5, W[4], W[5], 0.f, nullptr, nullptr);
    launch_g00(gsq, stream, W[4], W[5], D[0], D[1],
               W[0], W[1], 1.f, c2, nullptr, nullptr, 0.f, 0.f, nullptr, nullptr, 0.f, 0.f);
    eadd_k<<<gtr, ttr, 0, stream>>>(Mr, SC, c3, W[0], W[1], 0.f, nullptr, nullptr);
    launch_g00(gsq, stream, W[0], W[1], D[0], D[1],
               W[2], W[3], 1.f, 1.f, nullptr, nullptr, 0.f, 0.f, D[2], D[3], 1.f, 1.f);
    eadd_k<<<gtr, ttr, 0, stream>>>(Mr, SC, 1.f, W[2], W[3], -1.f, D[2], D[3]);
    launch_g00(gsq, stream, W[2], W[3], D[2], D[3],
               W[0], W[1], 1.f, 0.f, nullptr, nullptr, 0.f, 0.f, W[4], W[5], 1.f, 0.f);
    launch_g00(gsq, stream, W[0], W[1], W[4], W[5],
               W[2], W[3], 1.f, 0.f, nullptr, nullptr, 0.f, 0.f, D[2], D[3], 1.f, 0.f);
    launch_g00(gsq, stream, W[2], W[3], D[2], D[3],
               W[0], W[1], 1.f, 0.f, nullptr, nullptr, 0.f, 0.f, W[4], W[5], 1.f, 0.f);
    launch_g00(gsq, stream, W[0], W[1], W[4], W[5],
               W[2], W[3], 1.f, 0.f, nullptr, nullptr, 0.f, 0.f, D[2], D[3], 1.f, 0.f);
    launch_g00(gsq, stream, W[2], W[3], D[2], D[3],
               nullptr, nullptr, 0.f, 0.f, nullptr, nullptr, 0.f, 0.f, D[0], D[1], 1.f, 0.f);

    // ---------------- chain B (Mi) -> EB_B @ (W0,W1) ----------------
    skew_split_k<<<gtr, ttr, 0, stream>>>(Mi, W[0], W[1], W[2], W[3], SC);
    gsplit_k<0,0><<<gsq, tb, 0, stream>>>(W[0], W[1], nullptr, nullptr, W[2], W[3],
        W[4], W[5], c6, c4, D[2], D[3], 1.f, 0.f, nullptr, nullptr, 0.f, 0.f,
        nullptr, nullptr, nullptr);                                     // Y->(D2,D3)
    eadd_k<<<gtr, ttr, 0, stream>>>(Mi, SC, c5, W[4], W[5], 0.f, nullptr, nullptr);
    launch_g00(gsq, stream, W[4], W[5], D[2], D[3],
               W[0], W[1], 1.f, c2, nullptr, nullptr, 0.f, 0.f, nullptr, nullptr, 0.f, 0.f);
    eadd_k<<<gtr, ttr, 0, stream>>>(Mi, SC, c3, W[0], W[1], 0.f, nullptr, nullptr);
    launch_g00(gsq, stream, W[0], W[1], D[2], D[3],
               W[2], W[3], 1.f, 1.f, nullptr, nullptr, 0.f, 0.f, W[4], W[5], 1.f, 1.f);
    eadd_k<<<gtr, ttr, 0, stream>>>(Mi, SC, 1.f, W[2], W[3], -1.f, W[4], W[5]);
    launch_g00(gsq, stream, W[2], W[3], W[4], W[5],
               W[0], W[1], 1.f, 0.f, nullptr, nullptr, 0.f, 0.f, D[2], D[3], 1.f, 0.f);
    launch_g00(gsq, stream, W[0], W[1], D[2], D[3],
               W[2], W[3], 1.f, 0.f, nullptr, nullptr, 0.f, 0.f, W[4], W[5], 1.f, 0.f);
    launch_g00(gsq, stream, W[2], W[3], W[4], W[5],
               W[0], W[1], 1.f, 0.f, nullptr, nullptr, 0.f, 0.f, D[2], D[3], 1.f, 0.f);
    launch_g00(gsq, stream, W[0], W[1], D[2], D[3],
               W[2], W[3], 1.f, 0.f, nullptr, nullptr, 0.f, 0.f, W[4], W[5], 1.f, 0.f);
    launch_g00(gsq, stream, W[2], W[3], W[4], W[5],
               nullptr, nullptr, 0.f, 0.f, nullptr, nullptr, 0.f, 0.f, W[0], W[1], 1.f, 0.f);

    // ---------------- batch: out = ((nin*EA)*EB + bias)^2 * gate ----------------
    gsplit_k<1,1><<<gbt, tb, 0, stream>>>(nullptr, nullptr, inputs, rnorm, D[0], D[1],
        nullptr, nullptr, 0.f, 0.f, nullptr, nullptr, 0.f, 0.f, nullptr, nullptr, 0.f, 0.f,
        Yws, nullptr, nullptr);
    gsplit_k<1,2><<<gbt, tb, 0, stream>>>(nullptr, nullptr, Yws, nullptr, W[0], W[1],
        nullptr, nullptr, 0.f, 0.f, nullptr, nullptr, 0.f, 0.f, nullptr, nullptr, 0.f, 0.f,
        out, bias, gatew);

    (void)in_sizes; (void)n_in; (void)out_size; (void)ws_size;
}

// Round 3
// 2937.658 us; speedup vs baseline: 2.0356x; 1.1195x over previous
//
#include <hip/hip_runtime.h>
#include <math.h>

#define SD 2048
#define BDIM 4096

typedef _Float16 f16;
using f16x8 = __attribute__((ext_vector_type(8))) f16;
using f16x4 = __attribute__((ext_vector_type(4))) f16;
using f32x4 = __attribute__((ext_vector_type(4))) float;

#define EPS_CROSS 4.8828125e-4f   // 2^-11
#define LSCALE    2048.0f         // 2^11

__device__ __forceinline__ void fsplit(float x, f16& h, f16& l) {
    h = (f16)x;
    l = (f16)((x - (float)h) * LSCALE);
}
__device__ __forceinline__ float fcomb(f16 h, f16 l) {
    return (float)h + (float)l * EPS_CROSS;
}
__device__ __forceinline__ float f4get(const float4& v, int j) {
    return j == 0 ? v.x : j == 1 ? v.y : j == 2 ? v.z : v.w;
}

struct GArgs {
    const f16 *Ah, *Al;
    const float *A32, *Asc;
    const f16 *Bh, *Bl;
    f16 *CAh, *CAl; float sA, dA;
    f16 *C2h, *C2l; float s2, d2;
    f16 *CBh, *CBl; float sB, dB;
    float *C32; const float *bias; const float *gate;
};

// split-f16 MFMA GEMM; blockIdx.z selects arg set (fused independent chains).
template<int ASRC, int OUT>
__global__ __launch_bounds__(256, 2)
void gsplit_k(GArgs gz0, GArgs gz1)
{
    const GArgs g = (blockIdx.z == 0) ? gz0 : gz1;
    __shared__ f16 Ah[4*128*8], Al[4*128*8], Bh[4*64*8], Bl[4*64*8];
    const int tid  = threadIdx.x;
    const int row0 = blockIdx.y * 128, col0 = blockIdx.x * 64;

    const int srow = tid >> 1;
    const int sks  = (tid & 1) << 4;
    const int kg0  = (tid & 1) * 2;
    const int bcol = tid & 63;
    const int bkg  = tid >> 6;

    float ascale = 1.f;
    if (ASRC == 1) ascale = g.Asc ? g.Asc[row0 + srow] : 1.f;

    const size_t abase = (size_t)(row0 + srow) * SD;
    const size_t bbase = (size_t)(col0 + bcol) * SD;

    float4 ra[4], rb0, rb1;

    auto loadT = [&](int k0) {
        if (ASRC == 0) {
            ra[0] = *(const float4*)(g.Ah + abase + k0 + sks);
            ra[1] = *(const float4*)(g.Ah + abase + k0 + sks + 8);
            ra[2] = *(const float4*)(g.Al + abase + k0 + sks);
            ra[3] = *(const float4*)(g.Al + abase + k0 + sks + 8);
        } else {
            const float* p = g.A32 + abase + k0 + sks;
            ra[0] = *(const float4*)(p);
            ra[1] = *(const float4*)(p + 4);
            ra[2] = *(const float4*)(p + 8);
            ra[3] = *(const float4*)(p + 12);
        }
        rb0 = *(const float4*)(g.Bh + bbase + k0 + bkg*8);
        rb1 = *(const float4*)(g.Bl + bbase + k0 + bkg*8);
    };
    auto storeT = [&]() {
        if (ASRC == 0) {
            *(float4*)&Ah[((kg0+0)*128 + srow)*8] = ra[0];
            *(float4*)&Ah[((kg0+1)*128 + srow)*8] = ra[1];
            *(float4*)&Al[((kg0+0)*128 + srow)*8] = ra[2];
            *(float4*)&Al[((kg0+1)*128 + srow)*8] = ra[3];
        } else {
            f16x8 h0, h1, l0, l1;
            #pragma unroll
            for (int j = 0; j < 8; ++j) {
                f16 hh, ll;
                fsplit(f4get(ra[j >> 2], j & 3) * ascale, hh, ll);
                h0[j] = hh; l0[j] = ll;
                fsplit(f4get(ra[2 + (j >> 2)], j & 3) * ascale, hh, ll);
                h1[j] = hh; l1[j] = ll;
            }
            *(f16x8*)&Ah[((kg0+0)*128 + srow)*8] = h0;
            *(f16x8*)&Ah[((kg0+1)*128 + srow)*8] = h1;
            *(f16x8*)&Al[((kg0+0)*128 + srow)*8] = l0;
            *(f16x8*)&Al[((kg0+1)*128 + srow)*8] = l1;
        }
        *(float4*)&Bh[(bkg*64 + bcol)*8] = rb0;
        *(float4*)&Bl[(bkg*64 + bcol)*8] = rb1;
    };

    const int lane = tid & 63, lr = lane & 15, lg = lane >> 4;
    const int wm = (tid >> 6) & 1, wn = tid >> 7;

    f32x4 ch[4][2], cx[4][2];
    #pragma unroll
    for (int m = 0; m < 4; ++m)
    #pragma unroll
    for (int n = 0; n < 2; ++n) {
        ch[m][n] = (f32x4)0.f;
        cx[m][n] = (f32x4)0.f;
    }

    loadT(0);
    for (int k0 = 0; k0 < SD; k0 += 32) {
        __syncthreads();
        storeT();
        __syncthreads();
        if (k0 + 32 < SD) loadT(k0 + 32);

        f16x8 af[4][2], bf[2][2];
        #pragma unroll
        for (int m = 0; m < 4; ++m) {
            const int off = (lg*128 + wm*64 + m*16 + lr)*8;
            af[m][0] = *(const f16x8*)&Ah[off];
            af[m][1] = *(const f16x8*)&Al[off];
        }
        #pragma unroll
        for (int n = 0; n < 2; ++n) {
            const int off = (lg*64 + wn*32 + n*16 + lr)*8;
            bf[n][0] = *(const f16x8*)&Bh[off];
            bf[n][1] = *(const f16x8*)&Bl[off];
        }
        #pragma unroll
        for (int m = 0; m < 4; ++m)
        #pragma unroll
        for (int n = 0; n < 2; ++n) {
            ch[m][n] = __builtin_amdgcn_mfma_f32_16x16x32_f16(af[m][0], bf[n][0], ch[m][n], 0, 0, 0);
            cx[m][n] = __builtin_amdgcn_mfma_f32_16x16x32_f16(af[m][0], bf[n][1], cx[m][n], 0, 0, 0);
            cx[m][n] = __builtin_amdgcn_mfma_f32_16x16x32_f16(af[m][1], bf[n][0], cx[m][n], 0, 0, 0);
        }
    }

    const int rbb = row0 + wm*64, cbb = col0 + wn*32;
    #pragma unroll
    for (int m = 0; m < 4; ++m)
    #pragma unroll
    for (int n = 0; n < 2; ++n) {
        const int gr0 = rbb + m*16 + lg*4;
        const int gc  = cbb + n*16 + lr;
        float v[4];
        #pragma unroll
        for (int q = 0; q < 4; ++q)
            v[q] = ch[m][n][q] + EPS_CROSS * cx[m][n][q];

        if (OUT == 0) {
            if (g.CAh) {
                #pragma unroll
                for (int q = 0; q < 4; ++q) {
                    float va = g.sA * v[q] + ((gr0 + q) == gc ? g.dA : 0.f);
                    f16 h, l; fsplit(va, h, l);
                    g.CAh[(size_t)(gr0+q)*SD + gc] = h;
                    g.CAl[(size_t)(gr0+q)*SD + gc] = l;
                }
            }
            if (g.C2h) {
                #pragma unroll
                for (int q = 0; q < 4; ++q) {
                    float v2 = g.s2 * v[q] + ((gr0 + q) == gc ? g.d2 : 0.f);
                    f16 h, l; fsplit(v2, h, l);
                    g.C2h[(size_t)(gr0+q)*SD + gc] = h;
                    g.C2l[(size_t)(gr0+q)*SD + gc] = l;
                }
            }
            if (g.CBh) {
                f16x4 hb, lb;
                #pragma unroll
                for (int q = 0; q < 4; ++q) {
                    float vb = g.sB * v[q] + ((gr0 + q) == gc ? g.dB : 0.f);
                    f16 h, l; fsplit(vb, h, l);
                    hb[q] = h; lb[q] = l;
                }
                *(f16x4*)&g.CBh[(size_t)gc*SD + gr0] = hb;
                *(f16x4*)&g.CBl[(size_t)gc*SD + gr0] = lb;
            }
        } else {
            #pragma unroll
            for (int q = 0; q < 4; ++q) {
                float t = v[q] + g.bias[gc];
                g.C32[(size_t)(gr0+q)*SD + gc] = t * t * g.gate[gc];
            }
        }
    }
}

struct SArgs { const float* M; f16 *XAh, *XAl, *XBh, *XBl; };

__global__ __launch_bounds__(256)
void skew_split_k(SArgs sz0, SArgs sz1, float scale)
{
    const SArgs s = blockIdx.z ? sz1 : sz0;
    __shared__ float t1[32][33], t2[32][33];
    const int bx = blockIdx.x*32, by = blockIdx.y*32;
    const int tx = threadIdx.x, ty = threadIdx.y;
    #pragma unroll
    for (int r = 0; r < 32; r += 8) {
        t1[ty+r][tx] = s.M[(size_t)(by+ty+r)*SD + bx+tx];
        t2[ty+r][tx] = s.M[(size_t)(bx+ty+r)*SD + by+tx];
    }
    __syncthreads();
    #pragma unroll
    for (int r = 0; r < 32; r += 8) {
        float xs = (t1[ty+r][tx] - t2[tx][ty+r]) * scale;
        size_t idx = (size_t)(by+ty+r)*SD + bx+tx;
        f16 h, l;
        fsplit(xs, h, l);  s.XAh[idx] = h; s.XAl[idx] = l;
        fsplit(-xs, h, l); s.XBh[idx] = h; s.XBl[idx] = l;
    }
}

struct EArgs { const float* M; float cA; f16 *Ahp, *Alp; float cB; f16 *Bhp, *Blp; };

__global__ __launch_bounds__(256)
void eadd_k(EArgs ez0, EArgs ez1, float scale)
{
    const EArgs e = blockIdx.z ? ez1 : ez0;
    __shared__ float t1[32][33], t2[32][33];
    const int bx = blockIdx.x*32, by = blockIdx.y*32;
    const int tx = threadIdx.x, ty = threadIdx.y;
    #pragma unroll
    for (int r = 0; r < 32; r += 8) {
        t1[ty+r][tx] = e.M[(size_t)(by+ty+r)*SD + bx+tx];
        t2[ty+r][tx] = e.M[(size_t)(bx+ty+r)*SD + by+tx];
    }
    __syncthreads();
    #pragma unroll
    for (int r = 0; r < 32; r += 8) {
        float xs = (t1[ty+r][tx] - t2[tx][ty+r]) * scale;
        size_t idx = (size_t)(by+ty+r)*SD + bx+tx;
        f16 h, l;
        float va = fcomb(e.Ahp[idx], e.Alp[idx]) + e.cA * xs;
        fsplit(va, h, l); e.Ahp[idx] = h; e.Alp[idx] = l;
        if (e.Bhp) {
            float vb = fcomb(e.Bhp[idx], e.Blp[idx]) + e.cB * xs;
            fsplit(vb, h, l); e.Bhp[idx] = h; e.Blp[idx] = l;
        }
    }
}

__global__ __launch_bounds__(256)
void rownorm_k(const float* __restrict__ in, float* __restrict__ rn)
{
    const int row = blockIdx.x;
    const float4* p = (const float4*)(in + (size_t)row * SD);
    float ss = 0.f;
    for (int i = threadIdx.x; i < SD / 4; i += 256) {
        float4 v = p[i];
        ss += v.x*v.x + v.y*v.y + v.z*v.z + v.w*v.w;
    }
#pragma unroll
    for (int o = 32; o; o >>= 1) ss += __shfl_down(ss, o);
    __shared__ float part[4];
    if ((threadIdx.x & 63) == 0) part[threadIdx.x >> 6] = ss;
    __syncthreads();
    if (threadIdx.x == 0) {
        const float t = part[0] + part[1] + part[2] + part[3];
        rn[row] = 1.0f / sqrtf(fmaxf(t, 1e-12f));
    }
}

__global__ __launch_bounds__(256)
void softmax_k(const float* __restrict__ q, float* __restrict__ pws,
               float* __restrict__ pout)
{
    __shared__ float red[4];
    const int tid = threadIdx.x;
    float m = -INFINITY;
    for (int i = tid; i < SD; i += 256) m = fmaxf(m, q[i]);
#pragma unroll
    for (int o = 32; o; o >>= 1) m = fmaxf(m, __shfl_down(m, o));
    if ((tid & 63) == 0) red[tid >> 6] = m;
    __syncthreads();
    const float gm = fmaxf(fmaxf(red[0], red[1]), fmaxf(red[2], red[3]));
    float s = 0.f;
    for (int i = tid; i < SD; i += 256) s += expf(q[i] - gm);
#pragma unroll
    for (int o = 32; o; o >>= 1) s += __shfl_down(s, o);
    __syncthreads();
    if ((tid & 63) == 0) red[tid >> 6] = s;
    __syncthreads();
    const float inv = 1.0f / (red[0] + red[1] + red[2] + red[3]);
    for (int i = tid; i < SD; i += 256) {
        const float val = expf(q[i] - gm) * inv;
        pws[i] = val;
        pout[i] = val;
    }
}

// ------------- host-side scheduling -------------
struct Pair { f16* h; f16* l; };

static GArgs mkG(Pair A, Pair B, Pair CA, float sA, float dA,
                 Pair C2, float s2, float d2, Pair CB, float sB, float dB)
{
    GArgs g{};
    g.Ah = A.h; g.Al = A.l; g.A32 = nullptr; g.Asc = nullptr;
    g.Bh = B.h; g.Bl = B.l;
    g.CAh = CA.h; g.CAl = CA.l; g.sA = sA; g.dA = dA;
    g.C2h = C2.h; g.C2l = C2.l; g.s2 = s2; g.d2 = d2;
    g.CBh = CB.h; g.CBl = CB.l; g.sB = sB; g.dB = dB;
    g.C32 = nullptr; g.bias = nullptr; g.gate = nullptr;
    return g;
}

struct ChainBuf { Pair p[4]; const float* Msrc; bool finalB; };

#define SC (1.0f / 16.0f)   // s = 4 squarings; theta ~ 12.8/16 = 0.8

// degree-6 Taylor (Paterson-Stockmeyer) + 4 squarings; result -> p[1]
// (A-layout if !finalB, B-layout if finalB)
static void expm_sched(hipStream_t st, int nz, const ChainBuf& c0, const ChainBuf& c1)
{
    const float k2 = 0.5f, k3 = 1.f/6.f, k4 = 1.f/24.f, k5 = 1.f/120.f, k6 = 1.f/720.f;
    const Pair NP{nullptr, nullptr};
    const dim3 tb(256);
    const dim3 gsq(SD/64, SD/128, nz);
    const dim3 gtr(SD/32, SD/32, nz), ttr(32, 8);

    auto G = [&](GArgs a, GArgs b) { gsplit_k<0,0><<<gsq, tb, 0, st>>>(a, b); };
    auto E = [&](EArgs a, EArgs b) { eadd_k<<<gtr, ttr, 0, st>>>(a, b, SC); };

    // skew: X_A -> p0, X_B -> p1
    SArgs s0{c0.Msrc, c0.p[0].h, c0.p[0].l, c0.p[1].h, c0.p[1].l};
    SArgs s1{c1.Msrc, c1.p[0].h, c1.p[0].l, c1.p[1].h, c1.p[1].l};
    skew_split_k<<<gtr, ttr, 0, st>>>(s0, s1, SC);

    auto g1 = [&](const ChainBuf& c) {   // M0 = k6*Y + k4*I -> p2 ; Y -> p3
        return mkG(c.p[0], c.p[1], c.p[2], k6, k4, c.p[3], 1.f, 0.f, NP, 0.f, 0.f); };
    G(g1(c0), g1(c1));
    auto e1 = [&](const ChainBuf& c) {
        return EArgs{c.Msrc, k5, c.p[2].h, c.p[2].l, 0.f, nullptr, nullptr}; };
    E(e1(c0), e1(c1));
    auto g2 = [&](const ChainBuf& c) {   // M1 = M0*Y + k2*I -> p0
        return mkG(c.p[2], c.p[3], c.p[0], 1.f, k2, NP, 0.f, 0.f, NP, 0.f, 0.f); };
    G(g2(c0), g2(c1));
    auto e2 = [&](const ChainBuf& c) {
        return EArgs{c.Msrc, k3, c.p[0].h, c.p[0].l, 0.f, nullptr, nullptr}; };
    E(e2(c0), e2(c1));
    auto g3 = [&](const ChainBuf& c) {   // M2 = M1*Y + I -> p1 (A), p2 (B)
        return mkG(c.p[0], c.p[3], c.p[1], 1.f, 1.f, NP, 0.f, 0.f, c.p[2], 1.f, 1.f); };
    G(g3(c0), g3(c1));
    auto e3 = [&](const ChainBuf& c) {
        return EArgs{c.Msrc, 1.f, c.p[1].h, c.p[1].l, -1.f, c.p[2].h, c.p[2].l}; };
    E(e3(c0), e3(c1));

    auto sqF = [&](const ChainBuf& c, int ia, int ib, int oa, int ob) {
        return mkG(c.p[ia], c.p[ib], c.p[oa], 1.f, 0.f, NP, 0.f, 0.f, c.p[ob], 1.f, 0.f); };
    G(sqF(c0, 1, 2, 0, 3), sqF(c1, 1, 2, 0, 3));
    G(sqF(c0, 0, 3, 1, 2), sqF(c1, 0, 3, 1, 2));
    G(sqF(c0, 1, 2, 0, 3), sqF(c1, 1, 2, 0, 3));
    auto sqL = [&](const ChainBuf& c) {  // final: one layout only -> p1
        Pair ca = c.finalB ? NP : c.p[1];
        Pair cb = c.finalB ? c.p[1] : NP;
        return mkG(c.p[0], c.p[3], ca, 1.f, 0.f, NP, 0.f, 0.f, cb, 1.f, 0.f); };
    G(sqL(c0), sqL(c1));
}

extern "C" void kernel_launch(void* const* d_in, const int* in_sizes, int n_in,
                              void* d_out, int out_size, void* d_ws, size_t ws_size,
                              hipStream_t stream)
{
    const float* inputs = (const float*)d_in[0];
    const float* Mr     = (const float*)d_in[1];
    const float* Mi     = (const float*)d_in[2];
    const float* bias   = (const float*)d_in[3];
    const float* qg     = (const float*)d_in[4];
    float* out = (float*)d_out;

    const size_t PLANE = (size_t)SD * SD * sizeof(f16);   // 8 MB
    const size_t PAIRB = 2 * PLANE;                        // 16 MB
    char* wsb = (char*)d_ws;
    char* ob  = (char*)d_out;

    auto WP = [&](int i) { char* b = wsb + (size_t)i * PAIRB;
                           return Pair{(f16*)b, (f16*)(b + PLANE)}; };
    auto DP = [&](int i) { char* b = ob + (size_t)i * PAIRB;
                           return Pair{(f16*)b, (f16*)(b + PLANE)}; };

    const bool fused = ws_size >= 6 * PAIRB + 64 * 1024;
    const size_t smallOff = (fused ? 6 : 3) * PAIRB;
    float* rnorm = (float*)(wsb + smallOff);
    float* gatew = rnorm + 4096;
    float* gout  = out + (size_t)BDIM * SD;

    const dim3 tb(256);
    const dim3 gsq1(SD/64, SD/128, 1);
    const dim3 gbt(SD/64, BDIM/128, 1);

    rownorm_k<<<BDIM, tb, 0, stream>>>(inputs, rnorm);
    softmax_k<<<1, tb, 0, stream>>>(qg, gatew, gout);

    Pair EA, EB, UF;
    if (fused) {
        ChainBuf c0{{WP(0), WP(1), WP(2), WP(3)}, Mr, false};
        ChainBuf c1{{WP(4), WP(5), DP(0), DP(1)}, Mi, true};
        expm_sched(stream, 2, c0, c1);
        EA = WP(1); EB = WP(5); UF = WP(0);
    } else {
        ChainBuf c0{{WP(0), WP(1), DP(0), DP(1)}, Mr, false};
        expm_sched(stream, 1, c0, c0);
        ChainBuf c1{{WP(0), WP(2), DP(0), DP(1)}, Mi, true};
        expm_sched(stream, 1, c1, c1);
        EA = WP(1); EB = WP(2); UF = WP(0);
    }

    // U = EA * EB -> B-layout @ UF
    {
        GArgs u = mkG(EA, EB, Pair{nullptr,nullptr}, 0.f, 0.f,
                      Pair{nullptr,nullptr}, 0.f, 0.f, UF, 1.f, 0.f);
        gsplit_k<0,0><<<gsq1, tb, 0, stream>>>(u, u);
    }
    // out = ((rnorm .* inputs) @ U + bias)^2 * gate
    {
        GArgs b{};
        b.A32 = inputs; b.Asc = rnorm;
        b.Bh = UF.h; b.Bl = UF.l;
        b.C32 = out; b.bias = bias; b.gate = gatew;
        gsplit_k<1,2><<<gbt, tb, 0, stream>>>(b, b);
    }

    (void)in_sizes; (void)n_in; (void)out_size;
}

// Round 4
// 1179.955 us; speedup vs baseline: 5.0680x; 2.4896x over previous
//
#include <hip/hip_runtime.h>
#include <math.h>

#define SD 2048
#define BDIM 4096

typedef _Float16 f16;
using f16x8 = __attribute__((ext_vector_type(8))) f16;
using f32x4 = __attribute__((ext_vector_type(4))) float;

#define EPS_CROSS 4.8828125e-4f   // 2^-11
#define LSCALE    2048.0f         // 2^11

__device__ __forceinline__ void fsplit(float x, f16& h, f16& l) {
    h = (f16)x;
    l = (f16)((x - (float)h) * LSCALE);
}
__device__ __forceinline__ float fcomb(f16 h, f16 l) {
    return (float)h + (float)l * EPS_CROSS;
}
__device__ __forceinline__ void glds16(const void* g, void* l) {
    __builtin_amdgcn_global_load_lds(
        (const __attribute__((address_space(1))) unsigned int*)g,
        (__attribute__((address_space(3))) unsigned int*)l, 16, 0, 0);
}

struct GArgs {
    const f16 *Ah, *Al, *Bh, *Bl;
    f16 *CAh, *CAl; float sA, dA;
    f16 *C2h, *C2l; float s2, d2;
    f16 *CBh, *CBl; float sB, dB;
    float *C32; const float *bias, *gate;
};

// split-f16 MFMA GEMM, 128x128 tile, BK=32, global_load_lds staging,
// double-buffered LDS, single barrier per K-step, LDS-transposed epilogue.
// OUT 0: f16 hi/lo pair outputs (CA row-major, C2 row-major, CB transposed),
// OUT 2: fp32 fused ((v + bias)^2 * gate).
template<int OUT>
__global__ __launch_bounds__(256, 2)
void gsplit_k(GArgs gz0, GArgs gz1)
{
    const GArgs g = blockIdx.z ? gz1 : gz0;
    __shared__ char smem[65536];   // 2 x (Ah 8K | Al 8K | Bh 8K | Bl 8K)
    const int tid  = threadIdx.x;
    const int lane = tid & 63, wid = tid >> 6;
    const int row0 = blockIdx.y * 128, col0 = blockIdx.x * 128;

    // ---- staging constants: wave wid stages plane wid (0=Ah 1=Al 2=Bh 3=Bl)
    const int lrow = lane >> 2;                    // row within 16-row chunk
    const int gsl  = (lane & 3) ^ (lrow & 3);      // XOR-swizzled k-slot (involution)
    const f16* splane = (wid == 0) ? g.Ah : (wid == 1) ? g.Al
                      : (wid == 2) ? g.Bh : g.Bl;
    const int  sbase  = (wid < 2) ? row0 : col0;
    const size_t sgoff = (size_t)(sbase + lrow) * SD + gsl * 8;

    auto stage = [&](int buf, int k0) {
        char* lb = smem + buf * 32768 + wid * 8192;
        const f16* gp = splane + sgoff + k0;
        #pragma unroll
        for (int s = 0; s < 8; ++s)
            glds16(gp + (size_t)s * 16 * SD, lb + s * 1024);
    };

    // ---- fragment read offsets (swizzled to match source XOR)
    const int lr = lane & 15, lg = lane >> 4;
    const int wm = wid >> 1, wn = wid & 1;
    const int afo = (wm*64 + lr)*64 + ((lg ^ (lr & 3)) << 4);   // bytes in plane
    const int bfo = (wn*64 + lr)*64 + ((lg ^ (lr & 3)) << 4);

    f32x4 ch[4][4], cx[4][4];
    #pragma unroll
    for (int m = 0; m < 4; ++m)
    #pragma unroll
    for (int n = 0; n < 4; ++n) { ch[m][n] = (f32x4)0.f; cx[m][n] = (f32x4)0.f; }

    stage(0, 0);
    for (int kt = 0; kt < SD / 32; ++kt) {
        const int cur = kt & 1;
        __syncthreads();                       // drains vmcnt (stage kt) + lgkm
        if (kt + 1 < SD / 32) stage(cur ^ 1, (kt + 1) * 32);
        const char* base = smem + cur * 32768;
        f16x8 ah[4], al[4], bh[4], bl[4];
        #pragma unroll
        for (int m = 0; m < 4; ++m) {
            ah[m] = *(const f16x8*)(base +     0 + afo + m*1024);
            al[m] = *(const f16x8*)(base +  8192 + afo + m*1024);
        }
        #pragma unroll
        for (int n = 0; n < 4; ++n) {
            bh[n] = *(const f16x8*)(base + 16384 + bfo + n*1024);
            bl[n] = *(const f16x8*)(base + 24576 + bfo + n*1024);
        }
        #pragma unroll
        for (int m = 0; m < 4; ++m)
        #pragma unroll
        for (int n = 0; n < 4; ++n) {
            ch[m][n] = __builtin_amdgcn_mfma_f32_16x16x32_f16(ah[m], bh[n], ch[m][n], 0, 0, 0);
            cx[m][n] = __builtin_amdgcn_mfma_f32_16x16x32_f16(ah[m], bl[n], cx[m][n], 0, 0, 0);
            cx[m][n] = __builtin_amdgcn_mfma_f32_16x16x32_f16(al[m], bh[n], cx[m][n], 0, 0, 0);
        }
    }

    // ---- epilogue: C/D layout col=lane&15, row=(lane>>4)*4+q (m89)
    const int erow = wm*64 + lg*4;   // + m*16 + q
    const int ecol = wn*64 + lr;     // + n*16

    if (OUT == 0) {
        f16* lds16 = (f16*)smem;     // [128][136] (16B-aligned rows, bank-spread)
        auto dumpPlane = [&](f16* dst, bool transp) {
            #pragma unroll
            for (int i = 0; i < 8; ++i) {
                int chunk = i * 256 + tid;
                int r = chunk >> 4, cs = chunk & 15;
                f16x8 v = *(const f16x8*)(lds16 + r * 136 + cs * 8);
                size_t go = transp ? ((size_t)(col0 + r) * SD + row0 + cs * 8)
                                   : ((size_t)(row0 + r) * SD + col0 + cs * 8);
                *(f16x8*)(dst + go) = v;
            }
        };
        auto writePair = [&](f16* dh, f16* dl, float s, float d, bool transp) {
            #pragma unroll
            for (int pl = 0; pl < 2; ++pl) {
                __syncthreads();
                #pragma unroll
                for (int m = 0; m < 4; ++m)
                #pragma unroll
                for (int n = 0; n < 4; ++n)
                #pragma unroll
                for (int q = 0; q < 4; ++q) {
                    int rl = erow + m*16 + q, cl = ecol + n*16;
                    float v  = ch[m][n][q] + EPS_CROSS * cx[m][n][q];
                    float vv = s * v + (((row0 + rl) == (col0 + cl)) ? d : 0.f);
                    f16 h, l; fsplit(vv, h, l);
                    int idx = transp ? (cl * 136 + rl) : (rl * 136 + cl);
                    lds16[idx] = pl ? l : h;
                }
                __syncthreads();
                dumpPlane(pl ? dl : dh, transp);
            }
        };
        if (g.CAh) writePair(g.CAh, g.CAl, g.sA, g.dA, false);
        if (g.C2h) writePair(g.C2h, g.C2l, g.s2, g.d2, false);
        if (g.CBh) writePair(g.CBh, g.CBl, g.sB, g.dB, true);
    } else {
        float* lds32 = (float*)smem;  // [128][68]
        #pragma unroll
        for (int h = 0; h < 2; ++h) {
            __syncthreads();
            if (wn == h) {
                #pragma unroll
                for (int m = 0; m < 4; ++m)
                #pragma unroll
                for (int n = 0; n < 4; ++n) {
                    int cl = ecol + n*16;
                    float b  = g.bias[col0 + cl];
                    float ga = g.gate[col0 + cl];
                    #pragma unroll
                    for (int q = 0; q < 4; ++q) {
                        int rl = erow + m*16 + q;
                        float v = ch[m][n][q] + EPS_CROSS * cx[m][n][q];
                        float t = v + b;
                        lds32[rl*68 + (cl - h*64)] = t * t * ga;
                    }
                }
            }
            __syncthreads();
            #pragma unroll
            for (int i = 0; i < 8; ++i) {
                int chunk = i * 256 + tid;
                int r = chunk >> 4, cs = chunk & 15;
                float4 v = *(const float4*)(lds32 + r*68 + cs*4);
                *(float4*)(g.C32 + (size_t)(row0 + r) * SD + col0 + h*64 + cs*4) = v;
            }
        }
    }
}

struct SArgs { const float* M; f16 *XAh, *XAl, *XBh, *XBl; };

__global__ __launch_bounds__(256)
void skew_split_k(SArgs sz0, SArgs sz1, float scale)
{
    const SArgs s = blockIdx.z ? sz1 : sz0;
    __shared__ float t1[32][33], t2[32][33];
    const int bx = blockIdx.x*32, by = blockIdx.y*32;
    const int tx = threadIdx.x, ty = threadIdx.y;
    #pragma unroll
    for (int r = 0; r < 32; r += 8) {
        t1[ty+r][tx] = s.M[(size_t)(by+ty+r)*SD + bx+tx];
        t2[ty+r][tx] = s.M[(size_t)(bx+ty+r)*SD + by+tx];
    }
    __syncthreads();
    #pragma unroll
    for (int r = 0; r < 32; r += 8) {
        float xs = (t1[ty+r][tx] - t2[tx][ty+r]) * scale;
        size_t idx = (size_t)(by+ty+r)*SD + bx+tx;
        f16 h, l;
        fsplit(xs, h, l);  s.XAh[idx] = h; s.XAl[idx] = l;
        fsplit(-xs, h, l); s.XBh[idx] = h; s.XBl[idx] = l;
    }
}

struct EArgs { const float* M; float cA; f16 *Ahp, *Alp; float cB; f16 *Bhp, *Blp; };

__global__ __launch_bounds__(256)
void eadd_k(EArgs ez0, EArgs ez1, float scale)
{
    const EArgs e = blockIdx.z ? ez1 : ez0;
    __shared__ float t1[32][33], t2[32][33];
    const int bx = blockIdx.x*32, by = blockIdx.y*32;
    const int tx = threadIdx.x, ty = threadIdx.y;
    #pragma unroll
    for (int r = 0; r < 32; r += 8) {
        t1[ty+r][tx] = e.M[(size_t)(by+ty+r)*SD + bx+tx];
        t2[ty+r][tx] = e.M[(size_t)(bx+ty+r)*SD + by+tx];
    }
    __syncthreads();
    #pragma unroll
    for (int r = 0; r < 32; r += 8) {
        float xs = (t1[ty+r][tx] - t2[tx][ty+r]) * scale;
        size_t idx = (size_t)(by+ty+r)*SD + bx+tx;
        f16 h, l;
        float va = fcomb(e.Ahp[idx], e.Alp[idx]) + e.cA * xs;
        fsplit(va, h, l); e.Ahp[idx] = h; e.Alp[idx] = l;
        if (e.Bhp) {
            float vb = fcomb(e.Bhp[idx], e.Blp[idx]) + e.cB * xs;
            fsplit(vb, h, l); e.Bhp[idx] = h; e.Blp[idx] = l;
        }
    }
}

__global__ __launch_bounds__(256)
void rownorm_k(const float* __restrict__ in, float* __restrict__ rn)
{
    const int row = blockIdx.x;
    const float4* p = (const float4*)(in + (size_t)row * SD);
    float ss = 0.f;
    for (int i = threadIdx.x; i < SD / 4; i += 256) {
        float4 v = p[i];
        ss += v.x*v.x + v.y*v.y + v.z*v.z + v.w*v.w;
    }
#pragma unroll
    for (int o = 32; o; o >>= 1) ss += __shfl_down(ss, o);
    __shared__ float part[4];
    if ((threadIdx.x & 63) == 0) part[threadIdx.x >> 6] = ss;
    __syncthreads();
    if (threadIdx.x == 0) {
        const float t = part[0] + part[1] + part[2] + part[3];
        rn[row] = 1.0f / sqrtf(fmaxf(t, 1e-12f));
    }
}

// nin planes: hi/lo split of rnorm[row] * inputs
__global__ __launch_bounds__(256)
void nsplit_k(const float* __restrict__ in, const float* __restrict__ rn,
              f16* __restrict__ ph, f16* __restrict__ pl)
{
    const size_t gid  = (size_t)blockIdx.x * 256 + threadIdx.x;
    const size_t base = gid * 8;
    const float r = rn[(int)(base >> 11)];
    float4 a = *(const float4*)(in + base);
    float4 b = *(const float4*)(in + base + 4);
    float v[8] = {a.x, a.y, a.z, a.w, b.x, b.y, b.z, b.w};
    f16x8 h, l;
    #pragma unroll
    for (int j = 0; j < 8; ++j) {
        f16 hh, ll; fsplit(v[j] * r, hh, ll);
        h[j] = hh; l[j] = ll;
    }
    *(f16x8*)(ph + base) = h;
    *(f16x8*)(pl + base) = l;
}

__global__ __launch_bounds__(256)
void softmax_k(const float* __restrict__ q, float* __restrict__ pws,
               float* __restrict__ pout)
{
    __shared__ float red[4];
    const int tid = threadIdx.x;
    float m = -INFINITY;
    for (int i = tid; i < SD; i += 256) m = fmaxf(m, q[i]);
#pragma unroll
    for (int o = 32; o; o >>= 1) m = fmaxf(m, __shfl_down(m, o));
    if ((tid & 63) == 0) red[tid >> 6] = m;
    __syncthreads();
    const float gm = fmaxf(fmaxf(red[0], red[1]), fmaxf(red[2], red[3]));
    float s = 0.f;
    for (int i = tid; i < SD; i += 256) s += expf(q[i] - gm);
#pragma unroll
    for (int o = 32; o; o >>= 1) s += __shfl_down(s, o);
    __syncthreads();
    if ((tid & 63) == 0) red[tid >> 6] = s;
    __syncthreads();
    const float inv = 1.0f / (red[0] + red[1] + red[2] + red[3]);
    for (int i = tid; i < SD; i += 256) {
        const float val = expf(q[i] - gm) * inv;
        pws[i] = val;
        pout[i] = val;
    }
}

// ------------- host-side scheduling -------------
struct Pair { f16* h; f16* l; };

static GArgs mkG(Pair A, Pair B, Pair CA, float sA, float dA,
                 Pair C2, float s2, float d2, Pair CB, float sB, float dB)
{
    GArgs g{};
    g.Ah = A.h; g.Al = A.l; g.Bh = B.h; g.Bl = B.l;
    g.CAh = CA.h; g.CAl = CA.l; g.sA = sA; g.dA = dA;
    g.C2h = C2.h; g.C2l = C2.l; g.s2 = s2; g.d2 = d2;
    g.CBh = CB.h; g.CBl = CB.l; g.sB = sB; g.dB = dB;
    g.C32 = nullptr; g.bias = nullptr; g.gate = nullptr;
    return g;
}

struct ChainBuf { Pair p[4]; const float* Msrc; bool finalB; };

#define SC (1.0f / 16.0f)   // s = 4 squarings; theta ~ 12.8/16 = 0.8

// degree-6 Taylor (Paterson-Stockmeyer) + 4 squarings; result -> p[1]
static void expm_sched(hipStream_t st, int nz, const ChainBuf& c0, const ChainBuf& c1)
{
    const float k2 = 0.5f, k3 = 1.f/6.f, k4 = 1.f/24.f, k5 = 1.f/120.f, k6 = 1.f/720.f;
    const Pair NP{nullptr, nullptr};
    const dim3 tb(256);
    const dim3 gsq(SD/128, SD/128, nz);
    const dim3 gtr(SD/32, SD/32, nz), ttr(32, 8);

    auto G = [&](GArgs a, GArgs b) { gsplit_k<0><<<gsq, tb, 0, st>>>(a, b); };
    auto E = [&](EArgs a, EArgs b) { eadd_k<<<gtr, ttr, 0, st>>>(a, b, SC); };

    SArgs s0{c0.Msrc, c0.p[0].h, c0.p[0].l, c0.p[1].h, c0.p[1].l};
    SArgs s1{c1.Msrc, c1.p[0].h, c1.p[0].l, c1.p[1].h, c1.p[1].l};
    skew_split_k<<<gtr, ttr, 0, st>>>(s0, s1, SC);

    auto g1 = [&](const ChainBuf& c) {   // M0 = k6*Y + k4*I -> p2 ; Y -> p3
        return mkG(c.p[0], c.p[1], c.p[2], k6, k4, c.p[3], 1.f, 0.f, NP, 0.f, 0.f); };
    G(g1(c0), g1(c1));
    auto e1 = [&](const ChainBuf& c) {
        return EArgs{c.Msrc, k5, c.p[2].h, c.p[2].l, 0.f, nullptr, nullptr}; };
    E(e1(c0), e1(c1));
    auto g2 = [&](const ChainBuf& c) {   // M1 = M0*Y + k2*I -> p0
        return mkG(c.p[2], c.p[3], c.p[0], 1.f, k2, NP, 0.f, 0.f, NP, 0.f, 0.f); };
    G(g2(c0), g2(c1));
    auto e2 = [&](const ChainBuf& c) {
        return EArgs{c.Msrc, k3, c.p[0].h, c.p[0].l, 0.f, nullptr, nullptr}; };
    E(e2(c0), e2(c1));
    auto g3 = [&](const ChainBuf& c) {   // M2 = M1*Y + I -> p1 (A), p2 (B)
        return mkG(c.p[0], c.p[3], c.p[1], 1.f, 1.f, NP, 0.f, 0.f, c.p[2], 1.f, 1.f); };
    G(g3(c0), g3(c1));
    auto e3 = [&](const ChainBuf& c) {
        return EArgs{c.Msrc, 1.f, c.p[1].h, c.p[1].l, -1.f, c.p[2].h, c.p[2].l}; };
    E(e3(c0), e3(c1));

    auto sqF = [&](const ChainBuf& c, int ia, int ib, int oa, int ob) {
        return mkG(c.p[ia], c.p[ib], c.p[oa], 1.f, 0.f, NP, 0.f, 0.f, c.p[ob], 1.f, 0.f); };
    G(sqF(c0, 1, 2, 0, 3), sqF(c1, 1, 2, 0, 3));
    G(sqF(c0, 0, 3, 1, 2), sqF(c1, 0, 3, 1, 2));
    G(sqF(c0, 1, 2, 0, 3), sqF(c1, 1, 2, 0, 3));
    auto sqL = [&](const ChainBuf& c) {
        Pair ca = c.finalB ? NP : c.p[1];
        Pair cb = c.finalB ? c.p[1] : NP;
        return mkG(c.p[0], c.p[3], ca, 1.f, 0.f, NP, 0.f, 0.f, cb, 1.f, 0.f); };
    G(sqL(c0), sqL(c1));
}

extern "C" void kernel_launch(void* const* d_in, const int* in_sizes, int n_in,
                              void* d_out, int out_size, void* d_ws, size_t ws_size,
                              hipStream_t stream)
{
    const float* inputs = (const float*)d_in[0];
    const float* Mr     = (const float*)d_in[1];
    const float* Mi     = (const float*)d_in[2];
    const float* bias   = (const float*)d_in[3];
    const float* qg     = (const float*)d_in[4];
    float* out = (float*)d_out;

    const size_t PLANE = (size_t)SD * SD * sizeof(f16);   // 8 MB
    const size_t PAIRB = 2 * PLANE;                        // 16 MB
    char* wsb = (char*)d_ws;
    char* ob  = (char*)d_out;

    auto WP = [&](int i) { char* b = wsb + (size_t)i * PAIRB;
                           return Pair{(f16*)b, (f16*)(b + PLANE)}; };
    auto DP = [&](int i) { char* b = ob + (size_t)i * PAIRB;
                           return Pair{(f16*)b, (f16*)(b + PLANE)}; };

    const bool fused = ws_size >= 6 * PAIRB + 64 * 1024;
    const size_t smallOff = (fused ? 6 : 3) * PAIRB;
    float* rnorm = (float*)(wsb + smallOff);
    float* gatew = rnorm + 4096;
    float* gout  = out + (size_t)BDIM * SD;

    const dim3 tb(256);
    const dim3 gsq1(SD/128, SD/128, 1);
    const dim3 gbt(SD/128, BDIM/128, 1);

    rownorm_k<<<BDIM, tb, 0, stream>>>(inputs, rnorm);
    softmax_k<<<1, tb, 0, stream>>>(qg, gatew, gout);

    Pair EA, EB, UF;
    int ninSlotA, ninSlotB;
    if (fused) {
        ChainBuf c0{{WP(0), WP(1), WP(2), WP(3)}, Mr, false};
        ChainBuf c1{{WP(4), WP(5), DP(0), DP(1)}, Mi, true};
        expm_sched(stream, 2, c0, c1);
        EA = WP(1); EB = WP(5); UF = WP(0);
        ninSlotA = 2; ninSlotB = 3;
    } else {
        ChainBuf c0{{WP(0), WP(1), DP(0), DP(1)}, Mr, false};
        expm_sched(stream, 1, c0, c0);
        ChainBuf c1{{WP(0), WP(2), DP(0), DP(1)}, Mi, true};
        expm_sched(stream, 1, c1, c1);
        EA = WP(1); EB = WP(2); UF = WP(0);
        ninSlotA = 1; ninSlotB = 2;
    }

    // U = EA * EB -> B-layout @ UF
    {
        GArgs u = mkG(EA, EB, Pair{nullptr,nullptr}, 0.f, 0.f,
                      Pair{nullptr,nullptr}, 0.f, 0.f, UF, 1.f, 0.f);
        gsplit_k<0><<<gsq1, tb, 0, stream>>>(u, u);
    }
    // nin planes (rnorm .* inputs, hi/lo) into freed ws slots
    f16* ninh = (f16*)(wsb + (size_t)ninSlotA * PAIRB);
    f16* ninl = (f16*)(wsb + (size_t)ninSlotB * PAIRB);
    nsplit_k<<<(BDIM * SD / 8) / 256, tb, 0, stream>>>(inputs, rnorm, ninh, ninl);
    // out = (nin @ U + bias)^2 * gate
    {
        GArgs b{};
        b.Ah = ninh; b.Al = ninl;
        b.Bh = UF.h; b.Bl = UF.l;
        b.C32 = out; b.bias = bias; b.gate = gatew;
        gsplit_k<2><<<gbt, tb, 0, stream>>>(b, b);
    }

    (void)in_sizes; (void)n_in; (void)out_size;
}